// Round 5
// baseline (467.778 us; speedup 1.0000x reference)
//
#include <hip/hip_runtime.h>
#include <hip/hip_bf16.h>
#include <stdint.h>

typedef __attribute__((ext_vector_type(8))) short bf16x8;
typedef __attribute__((ext_vector_type(4))) float f32x4;

#define GLB(p) ((const __attribute__((address_space(1))) void*)(p))
#define LDSP(p) ((__attribute__((address_space(3))) void*)(p))

#define HW    3136
#define WIMG  56
#define PROW  58                 // padded row length (56 + 2 halo)
#define PNR   59                 // padded rows allocated (58 used + 1 overread row)
#define SIMG  (PNR * PROW)       // 3422 cells/image, 128 B each
#define C_IN  512

// RNE fp32 -> bf16
static __device__ __forceinline__ unsigned short f2bf(float f) {
    unsigned u = __builtin_bit_cast(unsigned, f);
    return (unsigned short)((u + 0x7FFFu + ((u >> 16) & 1u)) >> 16);
}

// ---------------- prep: weights -> bf16 (blocks 0..575) + s halo zero (blocks 576..607) ----
__global__ void prep_kernel(const float* __restrict__ wsq,
                            const float* __restrict__ w1,
                            const float* __restrict__ w3,
                            unsigned short* __restrict__ wsq_bf,
                            unsigned short* __restrict__ w1_bf,
                            unsigned short* __restrict__ w3r_bf,
                            unsigned short* __restrict__ s) {
    const int b = blockIdx.x, tid = threadIdx.x;
    if (b < 576) {
        int t = b * 256 + tid;
        if (t < 32768) wsq_bf[t] = f2bf(wsq[t]);
        if (t < 16384) w1_bf[t] = f2bf(w1[t]);
        // w3r[j][o][c] from w3[o][c][3][3]
        int j = t >> 14, rem = t & 16383;
        int o = rem >> 6, c = rem & 63;
        w3r_bf[t] = f2bf(w3[(o * 64 + c) * 9 + j]);
    } else {
        // halo cells consumed by e3 taps: row 0 full, row 57 full, cols {0,57} of rows 1..56
        const int img = b - 576;
        uint4* sn = (uint4*)(s + (size_t)img * SIMG * 64);   // 8 uint4 per cell
        uint4 z; z.x = z.y = z.z = z.w = 0;
        for (int t = tid; t < 1824; t += 256) {              // 228 cells * 8 chunks
            int cell = t >> 3, q = t & 7;
            int row, col;
            if (cell < 116) { row = (cell >= 58) ? 57 : 0; col = cell % 58; }
            else { int c2 = cell - 116; row = 1 + (c2 >> 1); col = (c2 & 1) * 57; }
            sn[(size_t)(row * PROW + col) * 8 + q] = z;
        }
    }
}

// ---------------- squeeze: s[n][p][c] (padded, swizzled NHWC bf16) ----------------
// grid (49, 32), block 256 (4 waves). Block: 64 out-ch x 64 cols, K=512.
// Wave w owns cols [hw0+16w, hw0+16w+16): per step 8 ds_read_b32 + 4 cvt_pk builds ONE
// B-frag feeding 4 MFMAs (A = all 64 out-ch from L2-hot wsq_bf). LDS reads = staged bytes.
__global__ __launch_bounds__(256, 4) void squeeze_kernel(
    const float* __restrict__ x, const float* __restrict__ b_sq,
    const unsigned short* __restrict__ wsq_bf, unsigned short* __restrict__ s)
{
    __shared__ uint8_t xs[2][8192];
    const int n = blockIdx.y, hw0 = blockIdx.x * 64;
    const int tid = threadIdx.x;
    const int w = tid >> 6, l = tid & 63, lx = l & 15, lk = l >> 4;

    const uint8_t* xbase = (const uint8_t*)(x + (size_t)n * C_IN * HW + hw0);

    auto stage = [&](int buf, int kb) {
        #pragma unroll
        for (int q = 0; q < 2; ++q) {
            int c = q * 256 + tid;            // 16B chunk 0..511
            int r = c >> 4, g = c & 15;       // r: channel row 0..31
            const uint8_t* src = xbase + (size_t)(kb * 32 + r) * (HW * 4)
                                       + ((g * 16) ^ (((r >> 3) & 3) << 6));
            __builtin_amdgcn_global_load_lds(GLB(src), LDSP(&xs[buf][c * 16]), 16, 0, 0);
        }
    };

    stage(0, 0);
    __syncthreads();

    f32x4 acc[4] = {};
    const unsigned short* ap = wsq_bf + lx * C_IN + lk * 8;
    const int colb4 = ((w * 16 + lx) * 4);
    const int swz = lk << 6;

    for (int kb = 0; kb < 16; ++kb) {
        const int cur = kb & 1;
        if (kb < 15) stage(cur ^ 1, kb + 1);
        const uint8_t* bbase = &xs[cur][lk * 2048 + (colb4 ^ swz)];
        float f[8];
        #pragma unroll
        for (int i = 0; i < 8; ++i) f[i] = *(const float*)(bbase + i * 256);
        union { uint32_t u[4]; bf16x8 v; } bb;
        #pragma unroll
        for (int h = 0; h < 4; ++h)
            asm("v_cvt_pk_bf16_f32 %0, %1, %2" : "=v"(bb.u[h]) : "v"(f[2*h]), "v"(f[2*h+1]));
        bf16x8 a[4];
        #pragma unroll
        for (int mt = 0; mt < 4; ++mt)
            a[mt] = *(const bf16x8*)(ap + mt * 16 * C_IN + kb * 32);
        #pragma unroll
        for (int mt = 0; mt < 4; ++mt)
            acc[mt] = __builtin_amdgcn_mfma_f32_16x16x32_bf16(a[mt], bb.v, acc[mt], 0, 0, 0);
        __syncthreads();
    }

    const int col = hw0 + w * 16 + lx;
    const int p = col + 59 + 2 * (col / WIMG);
    uint8_t* sn = (uint8_t*)s + (size_t)n * SIMG * 128 + (size_t)p * 128;
    const int psw = (p & 7) << 4;
    #pragma unroll
    for (int mt = 0; mt < 4; ++mt) {
        const int c0 = mt * 16 + lk * 4;
        float4 bias = *(const float4*)(b_sq + c0);
        const float* bp = (const float*)&bias;
        unsigned short v[4];
        #pragma unroll
        for (int r = 0; r < 4; ++r) v[r] = f2bf(fmaxf(acc[mt][r] + bp[r], 0.0f));
        uint2 pk;
        pk.x = (unsigned)v[0] | ((unsigned)v[1] << 16);
        pk.y = (unsigned)v[2] | ((unsigned)v[3] << 16);
        *(uint2*)(sn + ((c0 * 2) ^ psw)) = pk;
    }
}

// ---------------- expand: operand-swapped MFMA, LDS-staged s tile ----------------
// grid 6272 (XCD-swizzled), block 256 (4 waves). Block: 64 c_out (mt) x 64 cols.
// Wave (wm,wn): 32 c_out x 32 cols -> per (j,k0): 2 LDS a-frags + 2 L2-hot w-frags + 4 MFMA.
__global__ __launch_bounds__(256, 4) void expand_kernel(
    const unsigned short* __restrict__ s,
    const unsigned short* __restrict__ w1_bf,
    const unsigned short* __restrict__ w3r_bf,
    const float* __restrict__ b1, const float* __restrict__ b3,
    float* __restrict__ out)
{
    __shared__ uint8_t tile[37120];
    // XCD-aware swizzle: 6272 = 8 * 784; each XCD gets 4 images' full (mt,ht) range
    const int bid = blockIdx.x;
    const int ord = (bid & 7) * 784 + (bid >> 3);
    const int n = ord / 196;
    const int r2 = ord - n * 196;
    const int mt = r2 / 49;
    const int ht = r2 - mt * 49;
    const int hw0 = ht * 64, y0 = hw0 / WIMG;

    const int tid = threadIdx.x;
    const int w = tid >> 6, l = tid & 63, lx = l & 15, lk = l >> 4;
    const int wm = w >> 1, wn = w & 1;

    const uint8_t* src = (const uint8_t*)s + ((size_t)n * SIMG + y0 * PROW) * 128;
    #pragma unroll
    for (int it = 0; it < 9; ++it) {
        int c = it * 256 + tid;
        __builtin_amdgcn_global_load_lds(GLB(src + (size_t)c * 16), LDSP(&tile[c * 16]), 16, 0, 0);
    }
    if (tid < 16)
        __builtin_amdgcn_global_load_lds(GLB(src + (size_t)(2304 + tid) * 16),
                                         LDSP(&tile[(2304 + tid) * 16]), 16, 0, 0);
    __syncthreads();

    const int cb = mt * 64 + wm * 32;          // c_out base of this wave
    const int hb = hw0 + wn * 32;              // col base of this wave
    int pg[2], tb[2];
    #pragma unroll
    for (int nf = 0; nf < 2; ++nf) {
        int hw = hb + nf * 16 + lx;
        int p = hw + 59 + 2 * (hw / WIMG);
        pg[nf] = p;
        tb[nf] = (p - y0 * PROW) * 128;
    }
    const int lk16 = lk * 16;
    float* outn = out + (size_t)n * 512 * HW;

    // ---- e1 (K=64) ----
    {
        f32x4 acc[2][2] = {};
        #pragma unroll
        for (int k0 = 0; k0 < 2; ++k0) {
            bf16x8 bw[2], av[2];
            #pragma unroll
            for (int bt = 0; bt < 2; ++bt)
                bw[bt] = *(const bf16x8*)(w1_bf + (cb + bt * 16 + lx) * 64 + k0 * 32 + lk * 8);
            #pragma unroll
            for (int nf = 0; nf < 2; ++nf)
                av[nf] = *(const bf16x8*)&tile[tb[nf] + ((lk16 + k0 * 64) ^ ((pg[nf] & 7) << 4))];
            #pragma unroll
            for (int bt = 0; bt < 2; ++bt)
                #pragma unroll
                for (int nf = 0; nf < 2; ++nf)
                    acc[bt][nf] = __builtin_amdgcn_mfma_f32_16x16x32_bf16(av[nf], bw[bt], acc[bt][nf], 0, 0, 0);
        }
        #pragma unroll
        for (int bt = 0; bt < 2; ++bt) {
            float bias = b1[cb + bt * 16 + lx];
            float* op = outn + (size_t)(cb + bt * 16 + lx) * HW + hb + lk * 4;
            #pragma unroll
            for (int nf = 0; nf < 2; ++nf) {
                float4 v;
                v.x = fmaxf(acc[bt][nf][0] + bias, 0.0f);
                v.y = fmaxf(acc[bt][nf][1] + bias, 0.0f);
                v.z = fmaxf(acc[bt][nf][2] + bias, 0.0f);
                v.w = fmaxf(acc[bt][nf][3] + bias, 0.0f);
                *(float4*)(op + nf * 16) = v;
            }
        }
    }

    // ---- e3 (9 taps x K=64, halo zero => unconditional) ----
    {
        f32x4 acc[2][2] = {};
        #pragma unroll
        for (int j = 0; j < 9; ++j) {
            const int doff = (j / 3 - 1) * PROW + (j % 3 - 1);
            const unsigned short* wj = w3r_bf + j * 16384;
            #pragma unroll
            for (int k0 = 0; k0 < 2; ++k0) {
                bf16x8 bw[2], av[2];
                #pragma unroll
                for (int bt = 0; bt < 2; ++bt)
                    bw[bt] = *(const bf16x8*)(wj + (cb + bt * 16 + lx) * 64 + k0 * 32 + lk * 8);
                #pragma unroll
                for (int nf = 0; nf < 2; ++nf) {
                    int pt = pg[nf] + doff;
                    av[nf] = *(const bf16x8*)&tile[tb[nf] + doff * 128 +
                                                  ((lk16 + k0 * 64) ^ ((pt & 7) << 4))];
                }
                #pragma unroll
                for (int bt = 0; bt < 2; ++bt)
                    #pragma unroll
                    for (int nf = 0; nf < 2; ++nf)
                        acc[bt][nf] = __builtin_amdgcn_mfma_f32_16x16x32_bf16(av[nf], bw[bt], acc[bt][nf], 0, 0, 0);
            }
        }
        #pragma unroll
        for (int bt = 0; bt < 2; ++bt) {
            float bias = b3[cb + bt * 16 + lx];
            float* op = outn + (size_t)(256 + cb + bt * 16 + lx) * HW + hb + lk * 4;
            #pragma unroll
            for (int nf = 0; nf < 2; ++nf) {
                float4 v;
                v.x = fmaxf(acc[bt][nf][0] + bias, 0.0f);
                v.y = fmaxf(acc[bt][nf][1] + bias, 0.0f);
                v.z = fmaxf(acc[bt][nf][2] + bias, 0.0f);
                v.w = fmaxf(acc[bt][nf][3] + bias, 0.0f);
                *(float4*)(op + nf * 16) = v;
            }
        }
    }
}

extern "C" void kernel_launch(void* const* d_in, const int* in_sizes, int n_in,
                              void* d_out, int out_size, void* d_ws, size_t ws_size,
                              hipStream_t stream) {
    const float* x   = (const float*)d_in[0];
    const float* wsq = (const float*)d_in[1];
    const float* bsq = (const float*)d_in[2];
    const float* w1  = (const float*)d_in[3];
    const float* b1  = (const float*)d_in[4];
    const float* w3  = (const float*)d_in[5];
    const float* b3  = (const float*)d_in[6];
    float* out = (float*)d_out;

    unsigned short* wsq_bf = (unsigned short*)d_ws;       // 32768 shorts
    unsigned short* w1_bf  = wsq_bf + 32768;              // 16384
    unsigned short* w3r_bf = w1_bf + 16384;               // 147456
    unsigned short* s      = w3r_bf + 147456;             // 32*3422*64 bf16 padded+swizzled

    prep_kernel<<<608, 256, 0, stream>>>(wsq, w1, w3, wsq_bf, w1_bf, w3r_bf, s);
    squeeze_kernel<<<dim3(49, 32), 256, 0, stream>>>(x, bsq, wsq_bf, s);
    expand_kernel<<<6272, 256, 0, stream>>>(s, w1_bf, w3r_bf, b1, b3, out);
}